// Round 1
// baseline (754.868 us; speedup 1.0000x reference)
//
#include <hip/hip_runtime.h>
#include <hip/hip_bf16.h>
#include <stdint.h>

// Problem constants
#define BATCH 32
#define CIN   512
#define LLEN  4096
#define COUT  512
#define KW    3
#define KTOT  (CIN * KW)      // 1536
#define LPAD  (LLEN + 2)      // 4098 rows in qxT (zero row at 0 and 4097)
#define EPSQ  1e-8f

typedef __bf16 bf16x8 __attribute__((ext_vector_type(8)));
typedef float  floatx4 __attribute__((ext_vector_type(4)));

__device__ __forceinline__ void async_load16(const void* gptr, void* ldsptr) {
    __builtin_amdgcn_global_load_lds(
        (const __attribute__((address_space(1))) void*)gptr,
        (__attribute__((address_space(3))) void*)ldsptr,
        16, 0, 0);
}

// ---------------------------------------------------------------------------
// Kernel 1: zero the two padding rows (l = -1 and l = LLEN) of qxT per batch.
// qxT layout: [BATCH][LPAD][CIN] bf16, data rows at lp = l+1.
// 32 batches * 2 rows * 512 bf16 = 16384 uint32 writes.
__global__ void zero_pad_kernel(uint32_t* __restrict__ qxT_u32) {
    int idx = blockIdx.x * blockDim.x + threadIdx.x;   // 0..16383
    int b = idx >> 9;          // 512 uints per batch (2 rows x 256)
    int r = (idx >> 8) & 1;    // 0 -> row 0, 1 -> row LPAD-1
    int c = idx & 255;         // uint within row (row = 512 bf16 = 256 uints)
    size_t row = (size_t)b * LPAD + (r ? (LPAD - 1) : 0);
    qxT_u32[row * (CIN / 2) + c] = 0u;
}

// ---------------------------------------------------------------------------
// Kernel 2: quantize x (per C_in channel, symmetric int8) and transpose to
// qxT[b][l+1][i] (channel-contiguous), bf16 (q in [-128,127] is exact).
// Tile: 64 (i) x 64 (l), 256 threads, LDS transpose.
__global__ __launch_bounds__(256) void quantx_kernel(
        const float* __restrict__ x,
        const float* __restrict__ a_scale,
        __bf16* __restrict__ qxT) {
    __shared__ __bf16 qs[64][66];   // [l][i], pad 66 -> conflict-free
    const int i0 = blockIdx.x * 64;
    const int l0 = blockIdx.y * 64;
    const int b  = blockIdx.z;
    const int tid = threadIdx.x;
    const int r = tid >> 6;        // 0..3
    const int c = tid & 63;        // l within tile

    const float* xb = x + ((size_t)b * CIN + i0) * LLEN + l0;
    #pragma unroll
    for (int p = 0; p < 16; ++p) {
        int i = p * 4 + r;
        float s = fabsf(a_scale[i0 + i]) + EPSQ;
        float v = xb[(size_t)i * LLEN + c];
        float q = fminf(fmaxf(rintf(v / s), -128.0f), 127.0f);
        qs[c][i] = (__bf16)q;
    }
    __syncthreads();

    // write phase: packed 4B stores along i (coalesced)
    const int c2 = tid & 31;   // i-pair index
    const int rr = tid >> 5;   // 0..7
    uint32_t* outp = (uint32_t*)(qxT + ((size_t)b * LPAD + (l0 + 1)) * CIN + i0);
    #pragma unroll
    for (int p = 0; p < 8; ++p) {
        int l = p * 8 + rr;
        union { __bf16 h[2]; uint32_t u; } pk;
        pk.h[0] = qs[l][2 * c2];
        pk.h[1] = qs[l][2 * c2 + 1];
        outp[(size_t)l * (CIN / 2) + c2] = pk.u;
    }
}

// ---------------------------------------------------------------------------
// Kernel 3: fold weights: Wf[o][k*512+i] = clip(round(w[o][i][k]/sw[o])) * sa[i] * sw[o]
__global__ void wfold_kernel(
        const float* __restrict__ w,
        const float* __restrict__ a_scale,
        const float* __restrict__ w_scale,
        __bf16* __restrict__ Wf) {
    int idx = blockIdx.x * blockDim.x + threadIdx.x;
    if (idx >= COUT * KTOT) return;
    int o   = idx / KTOT;
    int rem = idx - o * KTOT;
    int k = rem >> 9;      // 0..2
    int i = rem & 511;
    float sw = fabsf(w_scale[o]) + EPSQ;
    float sa = fabsf(a_scale[i]) + EPSQ;
    float q = fminf(fmaxf(rintf(w[((size_t)o * CIN + i) * KW + k] / sw), -128.0f), 127.0f);
    Wf[idx] = (__bf16)(q * sa * sw);
}

// ---------------------------------------------------------------------------
// Kernel 4: GEMM. C[b][o][l] = sum_kk Wf[o][kk] * Xim[l][kk] + bias[o]
// where Xim[l][kk=(k,i)] = qxT[b][l+k][i]  (lp = l+k since data at l+1).
// 128x128 tile, BK=64, 4 waves each computing 64x64 via 4x4 of 16x16x32 MFMA.
__global__ __launch_bounds__(256) void qconv_gemm(
        const __bf16* __restrict__ Wf,
        const __bf16* __restrict__ qxT,
        const float* __restrict__ bias,
        float* __restrict__ out) {
    __shared__ __attribute__((aligned(16))) __bf16 Asmem[128 * 64];
    __shared__ __attribute__((aligned(16))) __bf16 Bsmem[128 * 64];

    const int tid  = threadIdx.x;
    const int m0   = blockIdx.x * 128;   // C_out tile (4)
    const int l0   = blockIdx.y * 128;   // L tile (32)
    const int b    = blockIdx.z;         // batch (32)
    const int wave = tid >> 6;
    const int lane = tid & 63;
    const int wm = wave >> 1, wn = wave & 1;
    const int row16 = lane & 15;
    const int quad  = lane >> 4;

    floatx4 acc[4][4];
    #pragma unroll
    for (int i = 0; i < 4; ++i)
        #pragma unroll
        for (int j = 0; j < 4; ++j)
            acc[i][j] = (floatx4){0.f, 0.f, 0.f, 0.f};

    const __bf16* qxb = qxT + (size_t)b * LPAD * CIN;

    for (int t = 0; t < KTOT / 64; ++t) {   // 24 iters
        const int kk0  = t * 64;
        const int kblk = kk0 >> 9;     // which tap (BK=64 never straddles a tap)
        const int i0   = kk0 & 511;

        // stage A tile: 128 rows x 64 bf16 = 16 KB = 1024 x 16B chunks
        #pragma unroll
        for (int j = 0; j < 4; ++j) {
            int chunk = j * 256 + tid;
            int arow  = chunk >> 3;
            int acol  = (chunk & 7) * 8;
            async_load16(Wf + (size_t)(m0 + arow) * KTOT + kk0 + acol,
                         (char*)Asmem + chunk * 16);
        }
        // stage B tile: 128 l-rows x 64 bf16
        #pragma unroll
        for (int j = 0; j < 4; ++j) {
            int chunk = j * 256 + tid;
            int brow  = chunk >> 3;
            int bcol  = (chunk & 7) * 8;
            async_load16(qxb + (size_t)(l0 + brow + kblk) * CIN + i0 + bcol,
                         (char*)Bsmem + chunk * 16);
        }
        __syncthreads();

        #pragma unroll
        for (int ks = 0; ks < 2; ++ks) {
            bf16x8 afrag[4], bfrag[4];
            #pragma unroll
            for (int mt = 0; mt < 4; ++mt) {
                int arow = wm * 64 + mt * 16 + row16;
                afrag[mt] = *(const bf16x8*)(Asmem + arow * 64 + ks * 32 + quad * 8);
            }
            #pragma unroll
            for (int nt = 0; nt < 4; ++nt) {
                int brow = wn * 64 + nt * 16 + row16;
                bfrag[nt] = *(const bf16x8*)(Bsmem + brow * 64 + ks * 32 + quad * 8);
            }
            #pragma unroll
            for (int mt = 0; mt < 4; ++mt)
                #pragma unroll
                for (int nt = 0; nt < 4; ++nt)
                    acc[mt][nt] = __builtin_amdgcn_mfma_f32_16x16x32_bf16(
                        afrag[mt], bfrag[nt], acc[mt][nt], 0, 0, 0);
        }
        __syncthreads();
    }

    // epilogue: C/D layout col=lane&15 (n=l), row=quad*4+reg (m=o)
    float* outb = out + (size_t)b * COUT * LLEN;
    #pragma unroll
    for (int mt = 0; mt < 4; ++mt) {
        #pragma unroll
        for (int r = 0; r < 4; ++r) {
            int o = m0 + wm * 64 + mt * 16 + quad * 4 + r;
            float bv = bias[o];
            #pragma unroll
            for (int nt = 0; nt < 4; ++nt) {
                int l = l0 + wn * 64 + nt * 16 + row16;
                outb[(size_t)o * LLEN + l] = acc[mt][nt][r] + bv;
            }
        }
    }
}

// ---------------------------------------------------------------------------
extern "C" void kernel_launch(void* const* d_in, const int* in_sizes, int n_in,
                              void* d_out, int out_size, void* d_ws, size_t ws_size,
                              hipStream_t stream) {
    const float* x       = (const float*)d_in[0];
    const float* weight  = (const float*)d_in[1];
    const float* bias    = (const float*)d_in[2];
    const float* a_scale = (const float*)d_in[3];
    const float* w_scale = (const float*)d_in[4];
    float* out = (float*)d_out;

    // workspace layout: Wf (bf16, 512*1536) then qxT (bf16, 32*4098*512)
    __bf16* Wf  = (__bf16*)d_ws;
    __bf16* qxT = (__bf16*)((char*)d_ws + (size_t)COUT * KTOT * sizeof(__bf16));

    wfold_kernel<<<dim3((COUT * KTOT) / 256), dim3(256), 0, stream>>>(
        weight, a_scale, w_scale, Wf);
    zero_pad_kernel<<<dim3(64), dim3(256), 0, stream>>>((uint32_t*)qxT);
    quantx_kernel<<<dim3(CIN / 64, LLEN / 64, BATCH), dim3(256), 0, stream>>>(
        x, a_scale, qxT);
    qconv_gemm<<<dim3(COUT / 128, LLEN / 128, BATCH), dim3(256), 0, stream>>>(
        Wf, qxT, bias, out);
}

// Round 3
// 719.299 us; speedup vs baseline: 1.0495x; 1.0495x over previous
//
#include <hip/hip_runtime.h>
#include <hip/hip_bf16.h>
#include <stdint.h>

// Problem constants
#define BATCH 32
#define CIN   512
#define LLEN  4096
#define COUT  512
#define KW    3
#define KTOT  (CIN * KW)      // 1536
#define LPAD  (LLEN + 2)      // 4098 rows in qxT (zero row at 0 and 4097)
#define EPSQ  1e-8f

typedef __bf16 bf16x8 __attribute__((ext_vector_type(8)));
typedef float  floatx4 __attribute__((ext_vector_type(4)));

__device__ __forceinline__ void async_load16(const void* gptr, void* ldsptr) {
    __builtin_amdgcn_global_load_lds(
        (const __attribute__((address_space(1))) void*)gptr,
        (__attribute__((address_space(3))) void*)ldsptr,
        16, 0, 0);
}

// ---------------------------------------------------------------------------
// Kernel 1: zero the two padding rows (l = -1 and l = LLEN) of qxT per batch.
__global__ void zero_pad_kernel(uint32_t* __restrict__ qxT_u32) {
    int idx = blockIdx.x * blockDim.x + threadIdx.x;   // 0..16383
    int b = idx >> 9;
    int r = (idx >> 8) & 1;
    int c = idx & 255;
    size_t row = (size_t)b * LPAD + (r ? (LPAD - 1) : 0);
    qxT_u32[row * (CIN / 2) + c] = 0u;
}

// ---------------------------------------------------------------------------
// Kernel 2: quantize x per C_in channel and transpose to qxT[b][l+1][i], bf16.
// Tile 64 ch x 64 l, 256 threads. float4 global reads (16B/lane), one exact
// divide per (thread,p) = 4 divides/thread, reciprocal-multiply per element,
// LDS transpose, 8B packed stores.
// NOTE: uint2 row stride is CIN/4 = 128 (R2 bug was 64).
__global__ __launch_bounds__(256) void quantx_kernel(
        const float* __restrict__ x,
        const float* __restrict__ a_scale,
        __bf16* __restrict__ qxT) {
    __shared__ __bf16 qs[64][66];   // [l][i], pad -> low-conflict
    const int i0 = blockIdx.x * 64;
    const int l0 = blockIdx.y * 64;
    const int b  = blockIdx.z;
    const int tid = threadIdx.x;

    // read phase: lanes f4 = tid&15 cover 64 l via float4; irow = tid>>4
    const int f4   = tid & 15;
    const int irow = tid >> 4;     // 0..15
    #pragma unroll
    for (int p = 0; p < 4; ++p) {
        int i = p * 16 + irow;
        float s = fabsf(a_scale[i0 + i]) + EPSQ;
        float inv = 1.0f / s;                         // exact, once per channel
        const floatx4* xrow = (const floatx4*)(x + ((size_t)(b * CIN + i0 + i)) * LLEN + l0);
        floatx4 v = xrow[f4];
        #pragma unroll
        for (int j = 0; j < 4; ++j) {
            float q = fminf(fmaxf(rintf(v[j] * inv), -128.0f), 127.0f);
            qs[f4 * 4 + j][i] = (__bf16)q;
        }
    }
    __syncthreads();

    // write phase: 16 lanes x 8B cover one 64-ch row segment (128B/row)
    const int c4 = tid & 15;       // 4-channel group
    const int rr = tid >> 4;       // 0..15
    uint2* outp = (uint2*)(qxT + ((size_t)b * LPAD + (l0 + 1)) * CIN + i0);
    #pragma unroll
    for (int p = 0; p < 4; ++p) {
        int l = p * 16 + rr;
        const uint32_t* qrow = (const uint32_t*)&qs[l][0];  // 4-aligned always
        uint2 u;
        u.x = qrow[2 * c4];
        u.y = qrow[2 * c4 + 1];
        outp[(size_t)l * (CIN / 4) + c4] = u;   // row stride = 512 bf16 = 128 uint2
    }
}

// ---------------------------------------------------------------------------
// Kernel 3: fold weights: Wf[o][k*512+i] = clip(round(w/sw)) * sa * sw (bf16)
__global__ void wfold_kernel(
        const float* __restrict__ w,
        const float* __restrict__ a_scale,
        const float* __restrict__ w_scale,
        __bf16* __restrict__ Wf) {
    int idx = blockIdx.x * blockDim.x + threadIdx.x;
    if (idx >= COUT * KTOT) return;
    int o   = idx / KTOT;
    int rem = idx - o * KTOT;
    int k = rem >> 9;
    int i = rem & 511;
    float sw = fabsf(w_scale[o]) + EPSQ;
    float sa = fabsf(a_scale[i]) + EPSQ;
    float q = fminf(fmaxf(rintf(w[((size_t)o * CIN + i) * KW + k] / sw), -128.0f), 127.0f);
    Wf[idx] = (__bf16)(q * sa * sw);
}

// ---------------------------------------------------------------------------
// Kernel 4: GEMM with XOR-swizzled LDS staging (bank-conflict-free ds_read_b128).
// LDS chunk slot c (16B) of row r holds global column-chunk c^(r&7).
__global__ __launch_bounds__(256) void qconv_gemm(
        const __bf16* __restrict__ Wf,
        const __bf16* __restrict__ qxT,
        const float* __restrict__ bias,
        float* __restrict__ out) {
    __shared__ __attribute__((aligned(16))) __bf16 Asmem[128 * 64];
    __shared__ __attribute__((aligned(16))) __bf16 Bsmem[128 * 64];

    const int tid  = threadIdx.x;
    const int m0   = blockIdx.x * 128;
    const int l0   = blockIdx.y * 128;
    const int b    = blockIdx.z;
    const int wave = tid >> 6;
    const int lane = tid & 63;
    const int wm = wave >> 1, wn = wave & 1;
    const int row16 = lane & 15;
    const int quad  = lane >> 4;

    floatx4 acc[4][4];
    #pragma unroll
    for (int i = 0; i < 4; ++i)
        #pragma unroll
        for (int j = 0; j < 4; ++j)
            acc[i][j] = (floatx4){0.f, 0.f, 0.f, 0.f};

    const __bf16* qxb = qxT + (size_t)b * LPAD * CIN;

    for (int t = 0; t < KTOT / 64; ++t) {   // 24 iters
        const int kk0  = t * 64;
        const int kblk = kk0 >> 9;     // tap index (BK=64 never straddles a tap)
        const int i0   = kk0 & 511;

        // stage A tile (XOR-swizzled columns; LDS dst stays lane-contiguous)
        #pragma unroll
        for (int j = 0; j < 4; ++j) {
            int chunk = j * 256 + tid;
            int arow  = chunk >> 3;
            int gcol  = (chunk & 7) ^ (arow & 7);
            async_load16(Wf + (size_t)(m0 + arow) * KTOT + kk0 + gcol * 8,
                         (char*)Asmem + chunk * 16);
        }
        // stage B tile (XOR-swizzled columns)
        #pragma unroll
        for (int j = 0; j < 4; ++j) {
            int chunk = j * 256 + tid;
            int brow  = chunk >> 3;
            int gcol  = (chunk & 7) ^ (brow & 7);
            async_load16(qxb + (size_t)(l0 + brow + kblk) * CIN + i0 + gcol * 8,
                         (char*)Bsmem + chunk * 16);
        }
        __syncthreads();

        #pragma unroll
        for (int ks = 0; ks < 2; ++ks) {
            bf16x8 afrag[4], bfrag[4];
            #pragma unroll
            for (int mt = 0; mt < 4; ++mt) {
                int arow = wm * 64 + mt * 16 + row16;
                int js   = (ks * 4 + quad) ^ (arow & 7);
                afrag[mt] = *(const bf16x8*)(Asmem + arow * 64 + js * 8);
            }
            #pragma unroll
            for (int nt = 0; nt < 4; ++nt) {
                int brow = wn * 64 + nt * 16 + row16;
                int js   = (ks * 4 + quad) ^ (brow & 7);
                bfrag[nt] = *(const bf16x8*)(Bsmem + brow * 64 + js * 8);
            }
            #pragma unroll
            for (int mt = 0; mt < 4; ++mt)
                #pragma unroll
                for (int nt = 0; nt < 4; ++nt)
                    acc[mt][nt] = __builtin_amdgcn_mfma_f32_16x16x32_bf16(
                        afrag[mt], bfrag[nt], acc[mt][nt], 0, 0, 0);
        }
        __syncthreads();
    }

    // epilogue: C/D layout col=lane&15 (n=l), row=quad*4+reg (m=o)
    float* outb = out + (size_t)b * COUT * LLEN;
    #pragma unroll
    for (int mt = 0; mt < 4; ++mt) {
        #pragma unroll
        for (int r = 0; r < 4; ++r) {
            int o = m0 + wm * 64 + mt * 16 + quad * 4 + r;
            float bv = bias[o];
            #pragma unroll
            for (int nt = 0; nt < 4; ++nt) {
                int l = l0 + wn * 64 + nt * 16 + row16;
                outb[(size_t)o * LLEN + l] = acc[mt][nt][r] + bv;
            }
        }
    }
}

// ---------------------------------------------------------------------------
extern "C" void kernel_launch(void* const* d_in, const int* in_sizes, int n_in,
                              void* d_out, int out_size, void* d_ws, size_t ws_size,
                              hipStream_t stream) {
    const float* x       = (const float*)d_in[0];
    const float* weight  = (const float*)d_in[1];
    const float* bias    = (const float*)d_in[2];
    const float* a_scale = (const float*)d_in[3];
    const float* w_scale = (const float*)d_in[4];
    float* out = (float*)d_out;

    __bf16* Wf  = (__bf16*)d_ws;
    __bf16* qxT = (__bf16*)((char*)d_ws + (size_t)COUT * KTOT * sizeof(__bf16));

    wfold_kernel<<<dim3((COUT * KTOT) / 256), dim3(256), 0, stream>>>(
        weight, a_scale, w_scale, Wf);
    zero_pad_kernel<<<dim3(64), dim3(256), 0, stream>>>((uint32_t*)qxT);
    quantx_kernel<<<dim3(CIN / 64, LLEN / 64, BATCH), dim3(256), 0, stream>>>(
        x, a_scale, qxT);
    qconv_gemm<<<dim3(COUT / 128, LLEN / 128, BATCH), dim3(256), 0, stream>>>(
        Wf, qxT, bias, out);
}